// Round 1
// baseline (316.039 us; speedup 1.0000x reference)
//
#include <hip/hip_runtime.h>
#include <math.h>

#define EPS 1e-6f

// tanh(x) = sign(x) * (1 - 2/(1 + e^{2|x|}))
__device__ __forceinline__ float tanh_fast(float x) {
    float ax = fabsf(x);
    float e  = __expf(ax + ax);                 // e^{2|x|}; inf for large -> t=1
    float t  = 1.0f - __fdividef(2.0f, e + 1.0f);
    return copysignf(t, x);
}

// ---------------- Kernel 1: h = LayerNorm(relu(x @ Wh + bh)) ----------------
// grid: 64 blocks (one per batch row), 256 threads; thread t handles cols 2t,2t+1
__global__ __launch_bounds__(256) void k_fch_ln(
    const float* __restrict__ x, const float* __restrict__ Wh,
    const float* __restrict__ bh, const float* __restrict__ ls,
    const float* __restrict__ lb, float* __restrict__ hout) {
    const int b = blockIdx.x;
    const int t = threadIdx.x;
    __shared__ float xs[512];
    __shared__ float wred[2][4];

    xs[t]       = x[b * 512 + t];
    xs[t + 256] = x[b * 512 + t + 256];
    __syncthreads();

    const int c = 2 * t;
    float2 acc = *(const float2*)(bh + c);
#pragma unroll 8
    for (int k = 0; k < 512; ++k) {
        float xv = xs[k];
        float2 w = *(const float2*)(Wh + k * 512 + c);
        acc.x = fmaf(xv, w.x, acc.x);
        acc.y = fmaf(xv, w.y, acc.y);
    }
    acc.x = fmaxf(acc.x, 0.0f);
    acc.y = fmaxf(acc.y, 0.0f);

    float s  = acc.x + acc.y;
    float ss = acc.x * acc.x + acc.y * acc.y;
#pragma unroll
    for (int m = 1; m < 64; m <<= 1) {
        s  += __shfl_xor(s, m);
        ss += __shfl_xor(ss, m);
    }
    const int wv = t >> 6;
    if ((t & 63) == 0) { wred[0][wv] = s; wred[1][wv] = ss; }
    __syncthreads();
    s  = wred[0][0] + wred[0][1] + wred[0][2] + wred[0][3];
    ss = wred[1][0] + wred[1][1] + wred[1][2] + wred[1][3];

    float mean = s * (1.0f / 512.0f);
    float var  = ss * (1.0f / 512.0f) - mean * mean;
    float rstd = rsqrtf(var + EPS);

    float2 sc = *(const float2*)(ls + c);
    float2 bi = *(const float2*)(lb + c);
    float2 o;
    o.x = (acc.x - mean) * rstd * sc.x + bi.x;
    o.y = (acc.y - mean) * rstd * sc.y + bi.y;
    *(float2*)(hout + b * 512 + c) = o;
}

// ---------------- Kernel 2: xz{1,2}[br] = x[br] @ Wz{1,2}[:512, :] ----------
// grid: (64, 16); y>>3 selects matrix, (y&7)*512 selects column chunk
__global__ __launch_bounds__(256) void k_xz(
    const float* __restrict__ x, const float* __restrict__ Wz1,
    const float* __restrict__ Wz2, float* __restrict__ xz1,
    float* __restrict__ xz2) {
    const int br   = blockIdx.x;
    const int half = blockIdx.y >> 3;
    const int cb   = (blockIdx.y & 7) * 512;
    const int t    = threadIdx.x;
    __shared__ float xs[512];
    xs[t]       = x[br * 512 + t];
    xs[t + 256] = x[br * 512 + t + 256];
    __syncthreads();

    const float* __restrict__ W   = half ? Wz2 : Wz1;
    float* __restrict__       out = half ? xz2 : xz1;
    const int c = cb + 2 * t;
    float2 acc = make_float2(0.0f, 0.0f);
#pragma unroll 8
    for (int k = 0; k < 512; ++k) {
        float xv = xs[k];
        float2 w = *(const float2*)(W + k * 4096 + c);
        acc.x = fmaf(xv, w.x, acc.x);
        acc.y = fmaf(xv, w.y, acc.y);
    }
    *(float2*)(out + br * 4096 + c) = acc;
}

// ---------------- Kernel 3: per-row bilinear + rownorm + tanh + dot ---------
// grid: 1024 blocks (one per row r = br*16 + a), 256 threads (4 waves)
__global__ __launch_bounds__(256, 2) void k_main(
    const float* __restrict__ xz1, const float* __restrict__ xz2,
    const float* __restrict__ Wz1, const float* __restrict__ Wz2,
    const float* __restrict__ hbuf, float* __restrict__ yout,
    float* __restrict__ qout) {
    const int r  = blockIdx.x;
    const int br = r >> 4, a = r & 15;
    const int t  = threadIdx.x;
    const int l  = t & 63, wv = t >> 6;

    __shared__ float z1s[8 * 512];
    __shared__ float z2s[8 * 512];
    __shared__ float Ag[512];
    __shared__ float Bg[512];
    __shared__ float ys[512];
    __shared__ float red[44 * 4];
    __shared__ float Ssum[44];
    __shared__ float wq[4];

    // ---- stage z1 = xz1[br] + Wz1[512+a], z2 likewise ----
    const float* __restrict__ w1r = Wz1 + (512 + a) * 4096;
    const float* __restrict__ w2r = Wz2 + (512 + a) * 4096;
    const float* __restrict__ x1  = xz1 + br * 4096;
    const float* __restrict__ x2  = xz2 + br * 4096;
#pragma unroll
    for (int i = 0; i < 4; ++i) {
        const int idx = (t + i * 256) * 4;
        float4 u = *(const float4*)(x1 + idx);
        float4 w = *(const float4*)(w1r + idx);
        u.x += w.x; u.y += w.y; u.z += w.z; u.w += w.w;
        *(float4*)(z1s + idx) = u;
        float4 u2 = *(const float4*)(x2 + idx);
        float4 w2 = *(const float4*)(w2r + idx);
        u2.x += w2.x; u2.y += w2.y; u2.z += w2.z; u2.w += w2.w;
        *(float4*)(z2s + idx) = u2;
    }
    __syncthreads();

    // ---- prepass: S1[h] = sum_d z1[h,d]; S2[h,h'] = sum_d z1[h,d]z1[h',d]
    {
        float zl0[8], zl1[8];
#pragma unroll
        for (int h = 0; h < 8; ++h) {
            zl0[h] = z1s[h * 512 + t];
            zl1[h] = z1s[h * 512 + t + 256];
        }
        float pm[8];
#pragma unroll
        for (int h = 0; h < 8; ++h) pm[h] = zl0[h] + zl1[h];
        float pg[36];
#pragma unroll
        for (int h = 0; h < 8; ++h) {
#pragma unroll
            for (int h2 = h; h2 < 8; ++h2) {
                const int id = 8 * h - (h * (h - 1)) / 2 + (h2 - h);
                pg[id] = zl0[h] * zl0[h2] + zl1[h] * zl1[h2];
            }
        }
#pragma unroll
        for (int m = 1; m < 64; m <<= 1) {
#pragma unroll
            for (int i = 0; i < 8; ++i) pm[i] += __shfl_xor(pm[i], m);
#pragma unroll
            for (int i = 0; i < 36; ++i) pg[i] += __shfl_xor(pg[i], m);
        }
        if (l == 0) {
#pragma unroll
            for (int i = 0; i < 8; ++i) red[i * 4 + wv] = pm[i];
#pragma unroll
            for (int i = 0; i < 36; ++i) red[(8 + i) * 4 + wv] = pg[i];
        }
    }
    __syncthreads();
    if (t < 44) Ssum[t] = red[t * 4 + 0] + red[t * 4 + 1] + red[t * 4 + 2] + red[t * 4 + 3];
    __syncthreads();

    // ---- per-g scale/bias: w_norm = acc * Ag[g] + Bg[g] ----
#pragma unroll
    for (int gi = 0; gi < 2; ++gi) {
        const int g = t + gi * 256;
        float z2v[8];
#pragma unroll
        for (int h = 0; h < 8; ++h) z2v[h] = z2s[h * 512 + g];
        float mean = 0.0f;
#pragma unroll
        for (int h = 0; h < 8; ++h) mean = fmaf(z2v[h], Ssum[h], mean);
        mean *= (1.0f / 512.0f);
        float e2 = 0.0f;
#pragma unroll
        for (int h = 0; h < 8; ++h) {
#pragma unroll
            for (int h2 = h; h2 < 8; ++h2) {
                const int id = 8 * h - (h * (h - 1)) / 2 + (h2 - h);
                float prod = z2v[h] * z2v[h2] * Ssum[8 + id];
                e2 += (h2 == h) ? prod : 2.0f * prod;
            }
        }
        e2 *= (1.0f / 512.0f);
        float var  = e2 - mean * mean;
        float sd   = sqrtf(fmaxf(var, 0.0f));
        float rstd = 1.0f / (sd + EPS);
        Ag[g] = rstd;
        Bg[g] = -mean * rstd;
    }
    __syncthreads();

    // ---- v fragment: lane owns float4 chunks l and 64+l of h[br] ----
    const float* __restrict__ vrow = hbuf + br * 512;
    const float4 vAv = *(const float4*)(vrow + 4 * l);
    const float4 vBv = *(const float4*)(vrow + 256 + 4 * l);
    const float vf[8] = {vAv.x, vAv.y, vAv.z, vAv.w, vBv.x, vBv.y, vBv.z, vBv.w};

    // ---- main loop: wave wv handles g in [wv*128, wv*128+128), 8 at a time --
    float qacc = 0.0f;
#pragma unroll 1
    for (int grp = 0; grp < 16; ++grp) {
        const int g0 = wv * 128 + grp * 8;
        float acc[8][8];
#pragma unroll
        for (int i = 0; i < 8; ++i)
#pragma unroll
            for (int j = 0; j < 8; ++j) acc[i][j] = 0.0f;

#pragma unroll
        for (int h = 0; h < 8; ++h) {
            const float4 p  = *(const float4*)(z1s + h * 512 + 4 * l);
            const float4 pq = *(const float4*)(z1s + h * 512 + 256 + 4 * l);
            const float4 ca = *(const float4*)(z2s + h * 512 + g0);
            const float4 cb = *(const float4*)(z2s + h * 512 + g0 + 4);
            const float zc[8] = {ca.x, ca.y, ca.z, ca.w, cb.x, cb.y, cb.z, cb.w};
#pragma unroll
            for (int gi = 0; gi < 8; ++gi) {
                acc[gi][0] = fmaf(zc[gi], p.x,  acc[gi][0]);
                acc[gi][1] = fmaf(zc[gi], p.y,  acc[gi][1]);
                acc[gi][2] = fmaf(zc[gi], p.z,  acc[gi][2]);
                acc[gi][3] = fmaf(zc[gi], p.w,  acc[gi][3]);
                acc[gi][4] = fmaf(zc[gi], pq.x, acc[gi][4]);
                acc[gi][5] = fmaf(zc[gi], pq.y, acc[gi][5]);
                acc[gi][6] = fmaf(zc[gi], pq.z, acc[gi][6]);
                acc[gi][7] = fmaf(zc[gi], pq.w, acc[gi][7]);
            }
        }

#pragma unroll
        for (int gi = 0; gi < 8; ++gi) {
            const float ag = Ag[g0 + gi];
            const float bg = Bg[g0 + gi];
            float yd = 0.0f;
#pragma unroll
            for (int k = 0; k < 8; ++k) {
                float wn = fmaf(acc[gi][k], ag, bg);
                yd = fmaf(tanh_fast(wn), vf[k], yd);
            }
#pragma unroll
            for (int m = 1; m < 64; m <<= 1) yd += __shfl_xor(yd, m);
            if (l == gi) ys[g0 + gi] = yd;
            qacc = fmaf(yd, yd, qacc);
        }
    }

    if (l == 0) wq[wv] = qacc;
    __syncthreads();
    if (t == 0) qout[r] = (wq[0] + wq[1] + wq[2] + wq[3]) * (1.0f / 512.0f);
    yout[r * 512 + t]       = ys[t];
    yout[r * 512 + t + 256] = ys[t + 256];
}

// ---------------------------------------------------------------------------
extern "C" void kernel_launch(void* const* d_in, const int* in_sizes, int n_in,
                              void* d_out, int out_size, void* d_ws, size_t ws_size,
                              hipStream_t stream) {
    const float* x   = (const float*)d_in[0];   // (64, 512)
    const float* Wh  = (const float*)d_in[1];   // (512, 512)
    const float* bh  = (const float*)d_in[2];   // (512,)
    const float* ls  = (const float*)d_in[3];   // (512,)
    const float* lb  = (const float*)d_in[4];   // (512,)
    const float* Wz1 = (const float*)d_in[5];   // (528, 4096)
    const float* Wz2 = (const float*)d_in[6];   // (528, 4096)

    float* out  = (float*)d_out;
    float* hout = out;                 // 64*512 = 32768
    float* qout = out + 32768;         // 64*16  = 1024
    float* yout = out + 33792;         // 1024*512 = 524288

    float* xz1 = (float*)d_ws;         // 64*4096 floats
    float* xz2 = xz1 + 64 * 4096;      // 64*4096 floats

    k_fch_ln<<<64, 256, 0, stream>>>(x, Wh, bh, ls, lb, hout);
    k_xz<<<dim3(64, 16), 256, 0, stream>>>(x, Wz1, Wz2, xz1, xz2);
    k_main<<<1024, 256, 0, stream>>>(xz1, xz2, Wz1, Wz2, hout, yout, qout);
}

// Round 2
// 228.836 us; speedup vs baseline: 1.3811x; 1.3811x over previous
//
#include <hip/hip_runtime.h>
#include <math.h>

#define EPS 1e-6f

typedef _Float16 half8 __attribute__((ext_vector_type(8)));
typedef float f32x16 __attribute__((ext_vector_type(16)));

// ---------------- Kernel 1: h = LayerNorm(relu(x @ Wh + bh)) ----------------
__global__ __launch_bounds__(256) void k_fch_ln(
    const float* __restrict__ x, const float* __restrict__ Wh,
    const float* __restrict__ bh, const float* __restrict__ ls,
    const float* __restrict__ lb, float* __restrict__ hout) {
    const int b = blockIdx.x;
    const int t = threadIdx.x;
    __shared__ float xs[512];
    __shared__ float wred[2][4];

    xs[t]       = x[b * 512 + t];
    xs[t + 256] = x[b * 512 + t + 256];
    __syncthreads();

    const int c = 2 * t;
    float2 acc = *(const float2*)(bh + c);
#pragma unroll 8
    for (int k = 0; k < 512; ++k) {
        float xv = xs[k];
        float2 w = *(const float2*)(Wh + k * 512 + c);
        acc.x = fmaf(xv, w.x, acc.x);
        acc.y = fmaf(xv, w.y, acc.y);
    }
    acc.x = fmaxf(acc.x, 0.0f);
    acc.y = fmaxf(acc.y, 0.0f);

    float s  = acc.x + acc.y;
    float ss = acc.x * acc.x + acc.y * acc.y;
#pragma unroll
    for (int m = 1; m < 64; m <<= 1) {
        s  += __shfl_xor(s, m);
        ss += __shfl_xor(ss, m);
    }
    const int wv = t >> 6;
    if ((t & 63) == 0) { wred[0][wv] = s; wred[1][wv] = ss; }
    __syncthreads();
    s  = wred[0][0] + wred[0][1] + wred[0][2] + wred[0][3];
    ss = wred[1][0] + wred[1][1] + wred[1][2] + wred[1][3];

    float mean = s * (1.0f / 512.0f);
    float var  = ss * (1.0f / 512.0f) - mean * mean;
    float rstd = rsqrtf(var + EPS);

    float2 sc = *(const float2*)(ls + c);
    float2 bi = *(const float2*)(lb + c);
    float2 o;
    o.x = (acc.x - mean) * rstd * sc.x + bi.x;
    o.y = (acc.y - mean) * rstd * sc.y + bi.y;
    *(float2*)(hout + b * 512 + c) = o;
}

// ---------------- Kernel 2: xz{1,2} = x @ Wz{1,2}[:512,:], 4 rows/block -----
// grid (16, 16): x = batch-group of 4; y: half = y>>3 (Wz1/Wz2), col chunk 512
__global__ __launch_bounds__(256) void k_xz(
    const float* __restrict__ x, const float* __restrict__ Wz1,
    const float* __restrict__ Wz2, float* __restrict__ xz1,
    float* __restrict__ xz2) {
    const int br0  = blockIdx.x * 4;
    const int half = blockIdx.y >> 3;
    const int cb   = (blockIdx.y & 7) * 512;
    const int t    = threadIdx.x;
    __shared__ float xs[4 * 512];
#pragma unroll
    for (int i = 0; i < 8; ++i) xs[t + i * 256] = x[br0 * 512 + t + i * 256];
    __syncthreads();

    const float* __restrict__ W   = half ? Wz2 : Wz1;
    float* __restrict__       out = half ? xz2 : xz1;
    const int c = cb + 2 * t;
    float2 a0 = {0.f, 0.f}, a1 = {0.f, 0.f}, a2 = {0.f, 0.f}, a3 = {0.f, 0.f};
#pragma unroll 4
    for (int k = 0; k < 512; ++k) {
        float2 w = *(const float2*)(W + k * 4096 + c);
        float x0 = xs[k], x1 = xs[512 + k], x2 = xs[1024 + k], x3 = xs[1536 + k];
        a0.x = fmaf(x0, w.x, a0.x); a0.y = fmaf(x0, w.y, a0.y);
        a1.x = fmaf(x1, w.x, a1.x); a1.y = fmaf(x1, w.y, a1.y);
        a2.x = fmaf(x2, w.x, a2.x); a2.y = fmaf(x2, w.y, a2.y);
        a3.x = fmaf(x3, w.x, a3.x); a3.y = fmaf(x3, w.y, a3.y);
    }
    *(float2*)(out + (br0 + 0) * 4096 + c) = a0;
    *(float2*)(out + (br0 + 1) * 4096 + c) = a1;
    *(float2*)(out + (br0 + 2) * 4096 + c) = a2;
    *(float2*)(out + (br0 + 3) * 4096 + c) = a3;
}

// ---------------- Kernel 3: MFMA bilinear + rownorm + tanh + dot ------------
// one block per row r; 256 threads = 4 waves; w = z2^T z1 via 32x32x16 f16 MFMA
__global__ __launch_bounds__(256, 4) void k_main(
    const float* __restrict__ xz1, const float* __restrict__ xz2,
    const float* __restrict__ Wz1, const float* __restrict__ Wz2,
    const float* __restrict__ hbuf, float* __restrict__ yout,
    float* __restrict__ qout) {
    const int r  = blockIdx.x;
    const int br = r >> 4, a = r & 15;
    const int t  = threadIdx.x;
    const int l  = t & 63, wv = t >> 6;
    const int hi = l >> 5, l31 = l & 31;

    __shared__ __align__(16) _Float16 z1t[513 * 8];   // [d][h], row 512 = zeros
    __shared__ __align__(16) _Float16 z2t[513 * 8];   // [g][h]
    __shared__ float2 ABs[512];                        // (Ag*2log2e, Bg*2log2e)
    __shared__ float  vs[512];
    __shared__ float  ys[512];
    __shared__ float  red[44 * 4];
    __shared__ float  Ssum[44];
    __shared__ float  wq[4];

    const float* __restrict__ x1  = xz1 + br * 4096;
    const float* __restrict__ x2  = xz2 + br * 4096;
    const float* __restrict__ w1r = Wz1 + (512 + a) * 4096;
    const float* __restrict__ w2r = Wz2 + (512 + a) * 4096;

    // ---- phase 1: stage z1,z2 (f16), stats from f16-rounded z1 ----
    float pm[8];
    float pg[36];
#pragma unroll
    for (int i = 0; i < 8; ++i) pm[i] = 0.f;
#pragma unroll
    for (int i = 0; i < 36; ++i) pg[i] = 0.f;

#pragma unroll
    for (int pass = 0; pass < 2; ++pass) {
        const int d = t + pass * 256;
        float z1v[8], z2v[8];
#pragma unroll
        for (int h = 0; h < 8; ++h) {
            z1v[h] = x1[h * 512 + d] + w1r[h * 512 + d];
            z2v[h] = x2[h * 512 + d] + w2r[h * 512 + d];
        }
        half8 h1, h2;
#pragma unroll
        for (int h = 0; h < 8; ++h) {
            h1[h] = (_Float16)z1v[h];
            h2[h] = (_Float16)z2v[h];
        }
        *(half8*)(z1t + d * 8) = h1;
        *(half8*)(z2t + d * 8) = h2;
        float zr[8];
#pragma unroll
        for (int h = 0; h < 8; ++h) zr[h] = (float)h1[h];
#pragma unroll
        for (int h = 0; h < 8; ++h) pm[h] += zr[h];
        int id = 0;
#pragma unroll
        for (int h = 0; h < 8; ++h)
#pragma unroll
            for (int h2_ = h; h2_ < 8; ++h2_) { pg[id] += zr[h] * zr[h2_]; ++id; }
    }
    if (t == 0) {
        half8 hz = {};
        *(half8*)(z1t + 512 * 8) = hz;
        *(half8*)(z2t + 512 * 8) = hz;
    }
    vs[t]       = hbuf[br * 512 + t];
    vs[t + 256] = hbuf[br * 512 + t + 256];

#pragma unroll
    for (int m = 1; m < 64; m <<= 1) {
#pragma unroll
        for (int i = 0; i < 8; ++i)  pm[i] += __shfl_xor(pm[i], m);
#pragma unroll
        for (int i = 0; i < 36; ++i) pg[i] += __shfl_xor(pg[i], m);
    }
    if (l == 0) {
#pragma unroll
        for (int i = 0; i < 8; ++i)  red[i * 4 + wv]       = pm[i];
#pragma unroll
        for (int i = 0; i < 36; ++i) red[(8 + i) * 4 + wv] = pg[i];
    }
    __syncthreads();
    if (t < 44) Ssum[t] = red[t * 4 + 0] + red[t * 4 + 1] + red[t * 4 + 2] + red[t * 4 + 3];
    __syncthreads();

    // ---- phase 2: per-g scale/bias (folded with 2*log2e) ----
    const float C2LE = 2.8853900817779268f;  // 2*log2(e)
#pragma unroll
    for (int pass = 0; pass < 2; ++pass) {
        const int g = t + pass * 256;
        half8 hz = *(const half8*)(z2t + g * 8);
        float zv[8];
#pragma unroll
        for (int h = 0; h < 8; ++h) zv[h] = (float)hz[h];
        float mean = 0.f;
#pragma unroll
        for (int h = 0; h < 8; ++h) mean = fmaf(zv[h], Ssum[h], mean);
        mean *= (1.0f / 512.0f);
        float e2 = 0.f;
        int id = 0;
#pragma unroll
        for (int h = 0; h < 8; ++h)
#pragma unroll
            for (int h2_ = h; h2_ < 8; ++h2_) {
                float p = zv[h] * zv[h2_] * Ssum[8 + id];
                e2 += (h2_ == h) ? p : 2.0f * p;
                ++id;
            }
        e2 *= (1.0f / 512.0f);
        float var  = e2 - mean * mean;
        float sd   = sqrtf(fmaxf(var, 0.f));
        float rstd = 1.0f / (sd + EPS);
        ABs[g] = make_float2(rstd * C2LE, -mean * rstd * C2LE);
    }
    __syncthreads();

    // ---- phase 3: MFMA tiles + finish ----
    const f32x16 CZ = {0.f, 0.f, 0.f, 0.f, 0.f, 0.f, 0.f, 0.f,
                       0.f, 0.f, 0.f, 0.f, 0.f, 0.f, 0.f, 0.f};
    float qacc = 0.f;
#pragma unroll 1
    for (int mi = 0; mi < 4; ++mi) {
        const int m0 = (wv * 4 + mi) * 32;
        const int arow = hi ? 512 : (m0 + l31);
        const half8 Af = *(const half8*)(z2t + arow * 8);
        float2 abv[16];
#pragma unroll
        for (int rg = 0; rg < 16; ++rg)
            abv[rg] = ABs[m0 + (rg & 3) + 8 * (rg >> 2) + 4 * hi];
        float yac[16];
#pragma unroll
        for (int i = 0; i < 16; ++i) yac[i] = 0.f;

#pragma unroll 1
        for (int nt = 0; nt < 16; ++nt) {
            const int n0 = nt * 32;
            const int brow = hi ? 512 : (n0 + l31);
            const half8 Bf = *(const half8*)(z1t + brow * 8);
            const float vv = vs[n0 + l31];
            f32x16 D = __builtin_amdgcn_mfma_f32_32x32x16_f16(Af, Bf, CZ, 0, 0, 0);
#pragma unroll
            for (int i = 0; i < 16; ++i) {
                float wn = fmaf(D[i], abv[i].x, abv[i].y);   // 2x * log2e
                float e  = exp2f(wn);                        // e^{2x}
                float sg = 1.0f - __fdividef(2.0f, e + 1.0f);
                yac[i] = fmaf(sg, vv, yac[i]);
            }
        }
#pragma unroll
        for (int i = 0; i < 16; ++i) {
#pragma unroll
            for (int m = 1; m <= 16; m <<= 1) yac[i] += __shfl_xor(yac[i], m);
        }
        if (l31 == 0) {
#pragma unroll
            for (int i = 0; i < 16; ++i) {
                const int g = m0 + (i & 3) + 8 * (i >> 2) + 4 * hi;
                ys[g] = yac[i];
                qacc = fmaf(yac[i], yac[i], qacc);
            }
        }
    }
    qacc += __shfl_xor(qacc, 32);
    if (l == 0) wq[wv] = qacc;
    __syncthreads();
    if (t == 0) qout[r] = (wq[0] + wq[1] + wq[2] + wq[3]) * (1.0f / 512.0f);
    yout[r * 512 + t]       = ys[t];
    yout[r * 512 + t + 256] = ys[t + 256];
}

// ---------------------------------------------------------------------------
extern "C" void kernel_launch(void* const* d_in, const int* in_sizes, int n_in,
                              void* d_out, int out_size, void* d_ws, size_t ws_size,
                              hipStream_t stream) {
    const float* x   = (const float*)d_in[0];   // (64, 512)
    const float* Wh  = (const float*)d_in[1];   // (512, 512)
    const float* bh  = (const float*)d_in[2];   // (512,)
    const float* ls  = (const float*)d_in[3];   // (512,)
    const float* lb  = (const float*)d_in[4];   // (512,)
    const float* Wz1 = (const float*)d_in[5];   // (528, 4096)
    const float* Wz2 = (const float*)d_in[6];   // (528, 4096)

    float* out  = (float*)d_out;
    float* hout = out;                 // 64*512
    float* qout = out + 32768;         // 64*16
    float* yout = out + 33792;         // 1024*512

    float* xz1 = (float*)d_ws;         // 64*4096 floats
    float* xz2 = xz1 + 64 * 4096;      // 64*4096 floats

    k_fch_ln<<<64, 256, 0, stream>>>(x, Wh, bh, ls, lb, hout);
    k_xz<<<dim3(16, 16), 256, 0, stream>>>(x, Wz1, Wz2, xz1, xz2);
    k_main<<<1024, 256, 0, stream>>>(xz1, xz2, Wz1, Wz2, hout, yout, qout);
}

// Round 3
// 135.614 us; speedup vs baseline: 2.3304x; 1.6874x over previous
//
#include <hip/hip_runtime.h>
#include <math.h>

#define EPS 1e-6f

typedef _Float16 half8 __attribute__((ext_vector_type(8)));
typedef float f32x16 __attribute__((ext_vector_type(16)));

// ---------------- Kernel 1: h = LayerNorm(relu(x @ Wh + bh)) ----------------
__global__ __launch_bounds__(256) void k_fch_ln(
    const float* __restrict__ x, const float* __restrict__ Wh,
    const float* __restrict__ bh, const float* __restrict__ ls,
    const float* __restrict__ lb, float* __restrict__ hout) {
    const int b = blockIdx.x;
    const int t = threadIdx.x;
    __shared__ float xs[512];
    __shared__ float wred[2][4];

    xs[t]       = x[b * 512 + t];
    xs[t + 256] = x[b * 512 + t + 256];
    __syncthreads();

    const int c = 2 * t;
    float2 acc = *(const float2*)(bh + c);
#pragma unroll 8
    for (int k = 0; k < 512; ++k) {
        float xv = xs[k];
        float2 w = *(const float2*)(Wh + k * 512 + c);
        acc.x = fmaf(xv, w.x, acc.x);
        acc.y = fmaf(xv, w.y, acc.y);
    }
    acc.x = fmaxf(acc.x, 0.0f);
    acc.y = fmaxf(acc.y, 0.0f);

    float s  = acc.x + acc.y;
    float ss = acc.x * acc.x + acc.y * acc.y;
#pragma unroll
    for (int m = 1; m < 64; m <<= 1) {
        s  += __shfl_xor(s, m);
        ss += __shfl_xor(ss, m);
    }
    const int wv = t >> 6;
    if ((t & 63) == 0) { wred[0][wv] = s; wred[1][wv] = ss; }
    __syncthreads();
    s  = wred[0][0] + wred[0][1] + wred[0][2] + wred[0][3];
    ss = wred[1][0] + wred[1][1] + wred[1][2] + wred[1][3];

    float mean = s * (1.0f / 512.0f);
    float var  = ss * (1.0f / 512.0f) - mean * mean;
    float rstd = rsqrtf(var + EPS);

    float2 sc = *(const float2*)(ls + c);
    float2 bi = *(const float2*)(lb + c);
    float2 o;
    o.x = (acc.x - mean) * rstd * sc.x + bi.x;
    o.y = (acc.y - mean) * rstd * sc.y + bi.y;
    *(float2*)(hout + b * 512 + c) = o;
}

// ---------------- Kernel 2: xz{1,2} = x @ Wz{1,2}[:512,:], 8 rows/block -----
// grid (8, 32): x -> batch-group of 8; y: half = y>>4, col chunk of 256
__global__ __launch_bounds__(256) void k_xz(
    const float* __restrict__ x, const float* __restrict__ Wz1,
    const float* __restrict__ Wz2, float* __restrict__ xz1,
    float* __restrict__ xz2) {
    const int br0  = blockIdx.x * 8;
    const int half = blockIdx.y >> 4;
    const int cb   = (blockIdx.y & 15) * 256;
    const int t    = threadIdx.x;
    __shared__ float xs[8 * 512];
#pragma unroll
    for (int i = 0; i < 16; ++i) xs[t + i * 256] = x[br0 * 512 + t + i * 256];
    __syncthreads();

    const float* __restrict__ W   = half ? Wz2 : Wz1;
    float* __restrict__       out = half ? xz2 : xz1;
    const float* __restrict__ Wc  = W + cb + t;

    float acc[8];
#pragma unroll
    for (int r = 0; r < 8; ++r) acc[r] = 0.f;

#pragma unroll 2
    for (int k4 = 0; k4 < 128; ++k4) {
        float4 xr[8];
#pragma unroll
        for (int r = 0; r < 8; ++r)
            xr[r] = *(const float4*)(xs + r * 512 + k4 * 4);
        const float* wp = Wc + (size_t)k4 * 4 * 4096;
        float w0 = wp[0], w1 = wp[4096], w2 = wp[8192], w3 = wp[12288];
#pragma unroll
        for (int r = 0; r < 8; ++r) {
            acc[r] = fmaf(xr[r].x, w0, acc[r]);
            acc[r] = fmaf(xr[r].y, w1, acc[r]);
            acc[r] = fmaf(xr[r].z, w2, acc[r]);
            acc[r] = fmaf(xr[r].w, w3, acc[r]);
        }
    }
#pragma unroll
    for (int r = 0; r < 8; ++r)
        out[(br0 + r) * 4096 + cb + t] = acc[r];
}

// ---------------- Kernel 3: MFMA bilinear + rownorm + tanh + dot ------------
// one block per row r; 256 threads = 4 waves; w = z2^T z1 via 32x32x16 f16 MFMA
__global__ __launch_bounds__(256, 4) void k_main(
    const float* __restrict__ xz1, const float* __restrict__ xz2,
    const float* __restrict__ Wz1, const float* __restrict__ Wz2,
    const float* __restrict__ hbuf, float* __restrict__ yout,
    float* __restrict__ qout) {
    const int r  = blockIdx.x;
    const int br = r >> 4, a = r & 15;
    const int t  = threadIdx.x;
    const int l  = t & 63, wv = t >> 6;
    const int hi = l >> 5, l31 = l & 31;

    __shared__ __align__(16) _Float16 z1t[513 * 8];   // [d][h], row 512 = zeros
    __shared__ __align__(16) _Float16 z2t[513 * 8];   // [g][h]
    __shared__ float2 ABs[512];                        // (Ag*2log2e, Bg*2log2e)
    __shared__ float  vs[512];
    __shared__ float  ys[512];
    __shared__ float  red[44 * 4];
    __shared__ float  Ssum[44];
    __shared__ float  wq[4];

    const float* __restrict__ x1  = xz1 + br * 4096;
    const float* __restrict__ x2  = xz2 + br * 4096;
    const float* __restrict__ w1r = Wz1 + (512 + a) * 4096;
    const float* __restrict__ w2r = Wz2 + (512 + a) * 4096;

    // ---- phase 1: stage z1,z2 (f16), stats from f16-rounded z1 ----
    float pm[8];
    float pg[36];
#pragma unroll
    for (int i = 0; i < 8; ++i) pm[i] = 0.f;
#pragma unroll
    for (int i = 0; i < 36; ++i) pg[i] = 0.f;

#pragma unroll
    for (int pass = 0; pass < 2; ++pass) {
        const int d = t + pass * 256;
        float z1v[8], z2v[8];
#pragma unroll
        for (int h = 0; h < 8; ++h) {
            z1v[h] = x1[h * 512 + d] + w1r[h * 512 + d];
            z2v[h] = x2[h * 512 + d] + w2r[h * 512 + d];
        }
        half8 h1, h2;
#pragma unroll
        for (int h = 0; h < 8; ++h) {
            h1[h] = (_Float16)z1v[h];
            h2[h] = (_Float16)z2v[h];
        }
        *(half8*)(z1t + d * 8) = h1;
        *(half8*)(z2t + d * 8) = h2;
        float zr[8];
#pragma unroll
        for (int h = 0; h < 8; ++h) zr[h] = (float)h1[h];
#pragma unroll
        for (int h = 0; h < 8; ++h) pm[h] += zr[h];
        int id = 0;
#pragma unroll
        for (int h = 0; h < 8; ++h)
#pragma unroll
            for (int h2_ = h; h2_ < 8; ++h2_) { pg[id] += zr[h] * zr[h2_]; ++id; }
    }
    if (t == 0) {
        half8 hz = {};
        *(half8*)(z1t + 512 * 8) = hz;
        *(half8*)(z2t + 512 * 8) = hz;
    }
    vs[t]       = hbuf[br * 512 + t];
    vs[t + 256] = hbuf[br * 512 + t + 256];

#pragma unroll
    for (int m = 1; m < 64; m <<= 1) {
#pragma unroll
        for (int i = 0; i < 8; ++i)  pm[i] += __shfl_xor(pm[i], m);
#pragma unroll
        for (int i = 0; i < 36; ++i) pg[i] += __shfl_xor(pg[i], m);
    }
    if (l == 0) {
#pragma unroll
        for (int i = 0; i < 8; ++i)  red[i * 4 + wv]       = pm[i];
#pragma unroll
        for (int i = 0; i < 36; ++i) red[(8 + i) * 4 + wv] = pg[i];
    }
    __syncthreads();
    if (t < 44) Ssum[t] = red[t * 4 + 0] + red[t * 4 + 1] + red[t * 4 + 2] + red[t * 4 + 3];
    __syncthreads();

    // ---- phase 2: per-g scale/bias (folded with 2*log2e) ----
    const float C2LE = 2.8853900817779268f;  // 2*log2(e)
#pragma unroll
    for (int pass = 0; pass < 2; ++pass) {
        const int g = t + pass * 256;
        half8 hz = *(const half8*)(z2t + g * 8);
        float zv[8];
#pragma unroll
        for (int h = 0; h < 8; ++h) zv[h] = (float)hz[h];
        float mean = 0.f;
#pragma unroll
        for (int h = 0; h < 8; ++h) mean = fmaf(zv[h], Ssum[h], mean);
        mean *= (1.0f / 512.0f);
        float e2 = 0.f;
        int id = 0;
#pragma unroll
        for (int h = 0; h < 8; ++h)
#pragma unroll
            for (int h2_ = h; h2_ < 8; ++h2_) {
                float p = zv[h] * zv[h2_] * Ssum[8 + id];
                e2 += (h2_ == h) ? p : 2.0f * p;
                ++id;
            }
        e2 *= (1.0f / 512.0f);
        float var  = e2 - mean * mean;
        float sd   = sqrtf(fmaxf(var, 0.f));
        float rstd = 1.0f / (sd + EPS);
        ABs[g] = make_float2(rstd * C2LE, -mean * rstd * C2LE);
    }
    __syncthreads();

    // ---- phase 3: MFMA tiles + finish (native exp2 + rcp: 4 VALU + 2 trans) -
    const f32x16 CZ = {0.f, 0.f, 0.f, 0.f, 0.f, 0.f, 0.f, 0.f,
                       0.f, 0.f, 0.f, 0.f, 0.f, 0.f, 0.f, 0.f};
    float qacc = 0.f;
#pragma unroll 1
    for (int mi = 0; mi < 4; ++mi) {
        const int m0 = (wv * 4 + mi) * 32;
        const int arow = hi ? 512 : (m0 + l31);
        const half8 Af = *(const half8*)(z2t + arow * 8);
        float2 abv[16];
#pragma unroll
        for (int rg = 0; rg < 16; ++rg)
            abv[rg] = ABs[m0 + (rg & 3) + 8 * (rg >> 2) + 4 * hi];
        float yac[16];
#pragma unroll
        for (int i = 0; i < 16; ++i) yac[i] = 0.f;

#pragma unroll 1
        for (int nt = 0; nt < 16; ++nt) {
            const int n0 = nt * 32;
            const int brow = hi ? 512 : (n0 + l31);
            const half8 Bf = *(const half8*)(z1t + brow * 8);
            const float vv = vs[n0 + l31];
            f32x16 D = __builtin_amdgcn_mfma_f32_32x32x16_f16(Af, Bf, CZ, 0, 0, 0);
#pragma unroll
            for (int i = 0; i < 16; ++i) {
                float wn = fmaf(D[i], abv[i].x, abv[i].y);     // 2x*log2e
                float e  = __builtin_amdgcn_exp2f(wn);         // e^{2x}
                float r1 = __builtin_amdgcn_rcpf(e + 1.0f);    // native rcp
                float sg = fmaf(-2.0f, r1, 1.0f);              // tanh(x)
                yac[i] = fmaf(sg, vv, yac[i]);
            }
        }
#pragma unroll
        for (int i = 0; i < 16; ++i) {
#pragma unroll
            for (int m = 1; m <= 16; m <<= 1) yac[i] += __shfl_xor(yac[i], m);
        }
        if (l31 == 0) {
#pragma unroll
            for (int i = 0; i < 16; ++i) {
                const int g = m0 + (i & 3) + 8 * (i >> 2) + 4 * hi;
                ys[g] = yac[i];
                qacc = fmaf(yac[i], yac[i], qacc);
            }
        }
    }
    qacc += __shfl_xor(qacc, 32);
    if (l == 0) wq[wv] = qacc;
    __syncthreads();
    if (t == 0) qout[r] = (wq[0] + wq[1] + wq[2] + wq[3]) * (1.0f / 512.0f);
    yout[r * 512 + t]       = ys[t];
    yout[r * 512 + t + 256] = ys[t + 256];
}

// ---------------------------------------------------------------------------
extern "C" void kernel_launch(void* const* d_in, const int* in_sizes, int n_in,
                              void* d_out, int out_size, void* d_ws, size_t ws_size,
                              hipStream_t stream) {
    const float* x   = (const float*)d_in[0];   // (64, 512)
    const float* Wh  = (const float*)d_in[1];   // (512, 512)
    const float* bh  = (const float*)d_in[2];   // (512,)
    const float* ls  = (const float*)d_in[3];   // (512,)
    const float* lb  = (const float*)d_in[4];   // (512,)
    const float* Wz1 = (const float*)d_in[5];   // (528, 4096)
    const float* Wz2 = (const float*)d_in[6];   // (528, 4096)

    float* out  = (float*)d_out;
    float* hout = out;                 // 64*512
    float* qout = out + 32768;         // 64*16
    float* yout = out + 33792;         // 1024*512

    float* xz1 = (float*)d_ws;         // 64*4096 floats
    float* xz2 = xz1 + 64 * 4096;      // 64*4096 floats

    k_fch_ln<<<64, 256, 0, stream>>>(x, Wh, bh, ls, lb, hout);
    k_xz<<<dim3(8, 32), 256, 0, stream>>>(x, Wz1, Wz2, xz1, xz2);
    k_main<<<1024, 256, 0, stream>>>(xz1, xz2, Wz1, Wz2, hout, yout, qout);
}